// Round 1
// baseline (229.161 us; speedup 1.0000x reference)
//
#include <hip/hip_runtime.h>

#define NB 4
#define NQ 256
#define NK 1024
#define ND 512
#define NH 128

// ---------------------------------------------------------------------------
// Kernel 1: row-major projection Y[row,h] = sum_d X[row,d] * W[d,h]
// X: (nrows, 512), W: (512, 128), Y: (nrows, 128). 8 rows per block.
// ---------------------------------------------------------------------------
__global__ __launch_bounds__(256) void proj_kernel(const float* __restrict__ X,
                                                   const float* __restrict__ W,
                                                   float* __restrict__ Y) {
  __shared__ float xs[8][ND];
  const int row0 = blockIdx.x * 8;
  {
    const float4* src = (const float4*)(X + (size_t)row0 * ND);
    float4* dst = (float4*)&xs[0][0];
    for (int i = threadIdx.x; i < 8 * ND / 4; i += 256) dst[i] = src[i];
  }
  __syncthreads();
  const int h = threadIdx.x & (NH - 1);
  const int r0 = (threadIdx.x >> 7) * 4;  // 0 or 4
  float acc0 = 0.f, acc1 = 0.f, acc2 = 0.f, acc3 = 0.f;
  for (int d = 0; d < ND; d += 4) {
    const float w0 = W[(d + 0) * NH + h];
    const float w1 = W[(d + 1) * NH + h];
    const float w2 = W[(d + 2) * NH + h];
    const float w3 = W[(d + 3) * NH + h];
    const float4 x0 = *(const float4*)&xs[r0 + 0][d];
    const float4 x1 = *(const float4*)&xs[r0 + 1][d];
    const float4 x2 = *(const float4*)&xs[r0 + 2][d];
    const float4 x3 = *(const float4*)&xs[r0 + 3][d];
    acc0 += x0.x * w0 + x0.y * w1 + x0.z * w2 + x0.w * w3;
    acc1 += x1.x * w0 + x1.y * w1 + x1.z * w2 + x1.w * w3;
    acc2 += x2.x * w0 + x2.y * w1 + x2.z * w2 + x2.w * w3;
    acc3 += x3.x * w0 + x3.y * w1 + x3.z * w2 + x3.w * w3;
  }
  Y[(size_t)(row0 + r0 + 0) * NH + h] = acc0;
  Y[(size_t)(row0 + r0 + 1) * NH + h] = acc1;
  Y[(size_t)(row0 + r0 + 2) * NH + h] = acc2;
  Y[(size_t)(row0 + r0 + 3) * NH + h] = acc3;
}

// ---------------------------------------------------------------------------
// Kernel 2: scores + masked softmax.
// Block handles (b, 4 q-rows). scores[q][k] = sum_h wv[h]*tanh(qh+kh),
// masked logits replaced by 0 (NOT -inf), softmax over all 1024 k.
// ---------------------------------------------------------------------------
__device__ __forceinline__ float fast_tanh(float x) {
  // tanh(x) = 1 - 2/(exp2(2*log2e*x)+1); exact at +/-inf saturation.
  const float e = __builtin_exp2f(2.8853900817779268f * x);
  return 1.0f - 2.0f * __builtin_amdgcn_rcpf(e + 1.0f);
}

__global__ __launch_bounds__(256) void scores_kernel(
    const float* __restrict__ qh, const float* __restrict__ kh,
    const float* __restrict__ wv, const int* __restrict__ vlen,
    float* __restrict__ attn) {
  constexpr int TQ = 4;   // q rows per block
  constexpr int KT = 64;  // k-tile staged in LDS
  __shared__ float qs[TQ][NH];
  __shared__ float wvs[NH];
  __shared__ float khs[KT][NH + 1];  // +1 pad: conflict-free lane-per-k reads
  __shared__ float sc[TQ][NK];

  const int b = blockIdx.x / (NQ / TQ);
  const int qt = blockIdx.x % (NQ / TQ);
  const int q0 = qt * TQ;
  const int t = threadIdx.x;

  for (int i = t; i < TQ * NH; i += 256)
    qs[i >> 7][i & (NH - 1)] = qh[(size_t)(b * NQ + q0 + (i >> 7)) * NH + (i & (NH - 1))];
  if (t < NH) wvs[t] = wv[t];
  const int vl = vlen[b];

  const int myk = t & 63;
  const int myq = t >> 6;

  for (int kt = 0; kt < NK; kt += KT) {
    __syncthreads();
    {
      const float4* src = (const float4*)(kh + (size_t)(b * NK + kt) * NH);
      for (int i = t; i < KT * NH / 4; i += 256) {
        const int r = i >> 5;          // /(NH/4)
        const int c = (i & 31) * 4;
        const float4 v = src[i];
        khs[r][c + 0] = v.x; khs[r][c + 1] = v.y;
        khs[r][c + 2] = v.z; khs[r][c + 3] = v.w;
      }
    }
    __syncthreads();
    const int k = kt + myk;
    float s = 0.f;
    #pragma unroll 8
    for (int h = 0; h < NH; ++h) {
      const float x = qs[myq][h] + khs[myk][h];
      s += wvs[h] * fast_tanh(x);
    }
    sc[myq][k] = (k < vl) ? s : 0.0f;
  }
  __syncthreads();

  // softmax: wave w handles q-row w
  const int wave = t >> 6, lane = t & 63;
  float m = -1e30f;
  for (int i = lane; i < NK; i += 64) m = fmaxf(m, sc[wave][i]);
  #pragma unroll
  for (int off = 32; off; off >>= 1) m = fmaxf(m, __shfl_xor(m, off));
  float sum = 0.f;
  for (int i = lane; i < NK; i += 64)
    sum += __builtin_exp2f(1.4426950408889634f * (sc[wave][i] - m));
  #pragma unroll
  for (int off = 32; off; off >>= 1) sum += __shfl_xor(sum, off);
  const float inv = 1.0f / sum;
  float* arow = attn + (size_t)(b * NQ + q0 + wave) * NK;
  for (int i = lane; i < NK; i += 64)
    arow[i] = __builtin_exp2f(1.4426950408889634f * (sc[wave][i] - m)) * inv;
}

// ---------------------------------------------------------------------------
// Kernel 3: out[b,q,d] = sum_k attn[b,q,k] * values[b,k,d]
// Tile: 16 q x 128 d per block; k staged in LDS tiles of 64.
// Thread: (t&31) -> 4 consecutive d; (t>>5) -> 2 q rows.
// ---------------------------------------------------------------------------
__global__ __launch_bounds__(256) void pv_kernel(const float* __restrict__ attn,
                                                 const float* __restrict__ values,
                                                 float* __restrict__ out) {
  constexpr int TQ = 16, TD = 128, KT = 64, ALS = KT + 4;  // stride 68: 16B-aligned rows
  __shared__ float als[TQ][ALS];
  const int tiles_d = ND / TD;                 // 4
  const int tiles_q = NQ / TQ;                 // 16
  const int bid = blockIdx.x;
  const int b = bid / (tiles_q * tiles_d);
  const int r = bid % (tiles_q * tiles_d);
  const int q0 = (r / tiles_d) * TQ;
  const int d0 = (r % tiles_d) * TD;
  const int t = threadIdx.x;
  const int dl = t & 31;
  const int qg = t >> 5;  // 0..7, each owns 2 q rows

  float4 acc0 = make_float4(0.f, 0.f, 0.f, 0.f);
  float4 acc1 = make_float4(0.f, 0.f, 0.f, 0.f);
  const float* vbase = values + (size_t)b * NK * ND + d0 + dl * 4;

  for (int kt = 0; kt < NK; kt += KT) {
    __syncthreads();
    {
      const int row = t >> 4, c4 = (t & 15) * 4;
      const float4 v = *(const float4*)(attn + (size_t)(b * NQ + q0 + row) * NK + kt + c4);
      *(float4*)&als[row][c4] = v;
    }
    __syncthreads();
    #pragma unroll 4
    for (int kk = 0; kk < KT; kk += 4) {
      const float4 a0 = *(const float4*)&als[qg * 2 + 0][kk];
      const float4 a1 = *(const float4*)&als[qg * 2 + 1][kk];
      const float* vp = vbase + (size_t)(kt + kk) * ND;
      const float4 v0 = *(const float4*)(vp);
      const float4 v1 = *(const float4*)(vp + ND);
      const float4 v2 = *(const float4*)(vp + 2 * ND);
      const float4 v3 = *(const float4*)(vp + 3 * ND);
      acc0.x += a0.x * v0.x + a0.y * v1.x + a0.z * v2.x + a0.w * v3.x;
      acc0.y += a0.x * v0.y + a0.y * v1.y + a0.z * v2.y + a0.w * v3.y;
      acc0.z += a0.x * v0.z + a0.y * v1.z + a0.z * v2.z + a0.w * v3.z;
      acc0.w += a0.x * v0.w + a0.y * v1.w + a0.z * v2.w + a0.w * v3.w;
      acc1.x += a1.x * v0.x + a1.y * v1.x + a1.z * v2.x + a1.w * v3.x;
      acc1.y += a1.x * v0.y + a1.y * v1.y + a1.z * v2.y + a1.w * v3.y;
      acc1.z += a1.x * v0.z + a1.y * v1.z + a1.z * v2.z + a1.w * v3.z;
      acc1.w += a1.x * v0.w + a1.y * v1.w + a1.z * v2.w + a1.w * v3.w;
    }
  }
  float* o0 = out + (size_t)(b * NQ + q0 + qg * 2 + 0) * ND + d0 + dl * 4;
  float* o1 = out + (size_t)(b * NQ + q0 + qg * 2 + 1) * ND + d0 + dl * 4;
  *(float4*)o0 = acc0;
  *(float4*)o1 = acc1;
}

// ---------------------------------------------------------------------------
extern "C" void kernel_launch(void* const* d_in, const int* in_sizes, int n_in,
                              void* d_out, int out_size, void* d_ws, size_t ws_size,
                              hipStream_t stream) {
  const float* queries = (const float*)d_in[0];  // (4,256,512)
  const float* keys    = (const float*)d_in[1];  // (4,1024,512)
  const float* values  = (const float*)d_in[2];  // (4,1024,512)
  const float* Wq      = (const float*)d_in[3];  // (512,128)
  const float* Wk      = (const float*)d_in[4];  // (512,128)
  const float* wv      = (const float*)d_in[5];  // (128,)
  const int*   vlen    = (const int*)d_in[6];    // (4,)
  float* out = (float*)d_out;                    // (4,256,512)

  float* qh   = (float*)d_ws;                    // 1024*128
  float* kh   = qh + (size_t)NB * NQ * NH;       // 4096*128
  float* attn = kh + (size_t)NB * NK * NH;       // 4*256*1024

  proj_kernel<<<(NB * NQ) / 8, 256, 0, stream>>>(queries, Wq, qh);
  proj_kernel<<<(NB * NK) / 8, 256, 0, stream>>>(keys, Wk, kh);
  scores_kernel<<<NB * (NQ / 4), 256, 0, stream>>>(qh, kh, wv, vlen, attn);
  pv_kernel<<<NB * (NQ / 16) * (ND / 128), 256, 0, stream>>>(attn, values, out);
}

// Round 2
// 158.104 us; speedup vs baseline: 1.4494x; 1.4494x over previous
//
#include <hip/hip_runtime.h>

#define NB 4
#define NQ 256
#define NK 1024
#define ND 512
#define NH 128

// ---------------------------------------------------------------------------
// Kernel 1: row-major projection Y[row,h] = sum_d X[row,d] * W[d,h]
// X: (nrows, 512), W: (512, 128), Y: (nrows, 128). 8 rows per block.
// ---------------------------------------------------------------------------
__global__ __launch_bounds__(256) void proj_kernel(const float* __restrict__ X,
                                                   const float* __restrict__ W,
                                                   float* __restrict__ Y) {
  __shared__ float xs[8][ND];
  const int row0 = blockIdx.x * 8;
  {
    const float4* src = (const float4*)(X + (size_t)row0 * ND);
    float4* dst = (float4*)&xs[0][0];
    for (int i = threadIdx.x; i < 8 * ND / 4; i += 256) dst[i] = src[i];
  }
  __syncthreads();
  const int h = threadIdx.x & (NH - 1);
  const int r0 = (threadIdx.x >> 7) * 4;  // 0 or 4
  float acc0 = 0.f, acc1 = 0.f, acc2 = 0.f, acc3 = 0.f;
  for (int d = 0; d < ND; d += 4) {
    const float w0 = W[(d + 0) * NH + h];
    const float w1 = W[(d + 1) * NH + h];
    const float w2 = W[(d + 2) * NH + h];
    const float w3 = W[(d + 3) * NH + h];
    const float4 x0 = *(const float4*)&xs[r0 + 0][d];
    const float4 x1 = *(const float4*)&xs[r0 + 1][d];
    const float4 x2 = *(const float4*)&xs[r0 + 2][d];
    const float4 x3 = *(const float4*)&xs[r0 + 3][d];
    acc0 += x0.x * w0 + x0.y * w1 + x0.z * w2 + x0.w * w3;
    acc1 += x1.x * w0 + x1.y * w1 + x1.z * w2 + x1.w * w3;
    acc2 += x2.x * w0 + x2.y * w1 + x2.z * w2 + x2.w * w3;
    acc3 += x3.x * w0 + x3.y * w1 + x3.z * w2 + x3.w * w3;
  }
  Y[(size_t)(row0 + r0 + 0) * NH + h] = acc0;
  Y[(size_t)(row0 + r0 + 1) * NH + h] = acc1;
  Y[(size_t)(row0 + r0 + 2) * NH + h] = acc2;
  Y[(size_t)(row0 + r0 + 3) * NH + h] = acc3;
}

// ---------------------------------------------------------------------------
// Kernel 2: raw masked scores. Block = (b, 4 q-rows, 256-k chunk).
// Grid = 4 * 64 * 4 = 1024 blocks -> 4 blocks/CU (LDS ~36KB), 50% occupancy.
// scores[q][k] = sum_h wv[h]*tanh(qh+kh); masked (k>=vl) -> 0.
// ---------------------------------------------------------------------------
__device__ __forceinline__ float fast_tanh(float x) {
  // tanh(x) = 1 - 2/(exp2(2*log2e*x)+1); exact saturation at +/-inf.
  const float e = __builtin_exp2f(2.8853900817779268f * x);
  return 1.0f - 2.0f * __builtin_amdgcn_rcpf(e + 1.0f);
}

__global__ __launch_bounds__(256) void scores_kernel(
    const float* __restrict__ qh, const float* __restrict__ kh,
    const float* __restrict__ wv, const int* __restrict__ vlen,
    float* __restrict__ attn) {
  constexpr int TQ = 4;    // q rows per block
  constexpr int KC = 256;  // k chunk per block
  constexpr int KT = 64;   // k subtile staged in LDS
  constexpr int KS = NH + 4;  // 132 floats: 16B-aligned rows, balanced banks
  __shared__ float qs[TQ][NH];
  __shared__ float wvs[NH];
  __shared__ float khs[KT][KS];

  const int bid = blockIdx.x;
  const int kc = bid & 3;
  const int qt = (bid >> 2) & 63;
  const int b = bid >> 8;
  const int q0 = qt * TQ;
  const int t = threadIdx.x;

  // stage q rows + wv (float4)
  if (t < TQ * NH / 4) {
    const int r = t >> 5, c = t & 31;
    ((float4*)&qs[r][0])[c] =
        ((const float4*)(qh + (size_t)(b * NQ + q0 + r) * NH))[c];
  }
  if (t >= 224) ((float4*)wvs)[t - 224] = ((const float4*)wv)[t - 224];
  const int vl = vlen[b];

  const int myk = t & 63;   // k within subtile
  const int myq = t >> 6;   // wave -> q row

  for (int s0 = 0; s0 < KC; s0 += KT) {
    __syncthreads();
    {
      const float4* src =
          (const float4*)(kh + (size_t)(b * NK + kc * KC + s0) * NH);
      for (int i = t; i < KT * NH / 4; i += 256) {
        const int r = i >> 5, c = i & 31;
        *(float4*)&khs[r][c * 4] = src[i];
      }
    }
    __syncthreads();
    const int k = kc * KC + s0 + myk;
    float s = 0.f;
    #pragma unroll 8
    for (int h = 0; h < NH; h += 4) {
      const float4 kv = *(const float4*)&khs[myk][h];
      const float4 qv = *(const float4*)&qs[myq][h];
      const float4 w4 = *(const float4*)&wvs[h];
      s += w4.x * fast_tanh(qv.x + kv.x);
      s += w4.y * fast_tanh(qv.y + kv.y);
      s += w4.z * fast_tanh(qv.z + kv.z);
      s += w4.w * fast_tanh(qv.w + kv.w);
    }
    attn[(size_t)(b * NQ + q0 + myq) * NK + k] = (k < vl) ? s : 0.0f;
  }
}

// ---------------------------------------------------------------------------
// Kernel 3: in-place masked softmax over each 1024-long row of attn.
// One wave per row; grid = 1024 blocks of 64 threads.
// ---------------------------------------------------------------------------
__global__ __launch_bounds__(64) void softmax_kernel(float* __restrict__ attn) {
  const int row = blockIdx.x;
  float4* a = (float4*)(attn + (size_t)row * NK);
  const int lane = threadIdx.x;
  float4 v[4];
  #pragma unroll
  for (int j = 0; j < 4; ++j) v[j] = a[lane + 64 * j];
  float m = -1e30f;
  #pragma unroll
  for (int j = 0; j < 4; ++j)
    m = fmaxf(m, fmaxf(fmaxf(v[j].x, v[j].y), fmaxf(v[j].z, v[j].w)));
  #pragma unroll
  for (int off = 32; off; off >>= 1) m = fmaxf(m, __shfl_xor(m, off));
  const float c = 1.4426950408889634f;
  float sum = 0.f;
  #pragma unroll
  for (int j = 0; j < 4; ++j) {
    v[j].x = __builtin_exp2f(c * (v[j].x - m));
    v[j].y = __builtin_exp2f(c * (v[j].y - m));
    v[j].z = __builtin_exp2f(c * (v[j].z - m));
    v[j].w = __builtin_exp2f(c * (v[j].w - m));
    sum += v[j].x + v[j].y + v[j].z + v[j].w;
  }
  #pragma unroll
  for (int off = 32; off; off >>= 1) sum += __shfl_xor(sum, off);
  const float inv = 1.0f / sum;
  #pragma unroll
  for (int j = 0; j < 4; ++j) {
    v[j].x *= inv; v[j].y *= inv; v[j].z *= inv; v[j].w *= inv;
    a[lane + 64 * j] = v[j];
  }
}

// ---------------------------------------------------------------------------
// Kernel 4: out[b,q,d] = sum_k attn[b,q,k] * values[b,k,d]
// Block = (b, 8 q-rows, 128 d). Grid = 4*32*4 = 512 blocks (2 blocks/CU).
// Full 8x1024 attn tile staged in LDS once (32KB) -> barrier-free main loop.
// Thread: dl = t&31 -> 4 consecutive d; qg = t>>5 -> 1 q row.
// ---------------------------------------------------------------------------
__global__ __launch_bounds__(256) void pv_kernel(const float* __restrict__ attn,
                                                 const float* __restrict__ values,
                                                 float* __restrict__ out) {
  constexpr int TQ = 8, TD = 128;
  __shared__ float als[TQ][NK];  // 32 KB
  const int bid = blockIdx.x;
  const int dt = bid & 3;
  const int qt = (bid >> 2) & 31;
  const int b = bid >> 7;
  const int q0 = qt * TQ;
  const int d0 = dt * TD;
  const int t = threadIdx.x;
  const int dl = t & 31;
  const int qg = t >> 5;

  {
    const float4* src = (const float4*)(attn + (size_t)(b * NQ + q0) * NK);
    float4* dst = (float4*)&als[0][0];
    for (int i = t; i < TQ * NK / 4; i += 256) dst[i] = src[i];
  }
  __syncthreads();

  float4 acc = make_float4(0.f, 0.f, 0.f, 0.f);
  const float* vbase = values + (size_t)b * NK * ND + d0 + dl * 4;

  #pragma unroll 2
  for (int k = 0; k < NK; k += 4) {
    const float4 a4 = *(const float4*)&als[qg][k];
    const float4 v0 = *(const float4*)(vbase + (size_t)(k + 0) * ND);
    const float4 v1 = *(const float4*)(vbase + (size_t)(k + 1) * ND);
    const float4 v2 = *(const float4*)(vbase + (size_t)(k + 2) * ND);
    const float4 v3 = *(const float4*)(vbase + (size_t)(k + 3) * ND);
    acc.x += a4.x * v0.x + a4.y * v1.x + a4.z * v2.x + a4.w * v3.x;
    acc.y += a4.x * v0.y + a4.y * v1.y + a4.z * v2.y + a4.w * v3.y;
    acc.z += a4.x * v0.z + a4.y * v1.z + a4.z * v2.z + a4.w * v3.z;
    acc.w += a4.x * v0.w + a4.y * v1.w + a4.z * v2.w + a4.w * v3.w;
  }
  *(float4*)(out + (size_t)(b * NQ + q0 + qg) * ND + d0 + dl * 4) = acc;
}

// ---------------------------------------------------------------------------
extern "C" void kernel_launch(void* const* d_in, const int* in_sizes, int n_in,
                              void* d_out, int out_size, void* d_ws, size_t ws_size,
                              hipStream_t stream) {
  const float* queries = (const float*)d_in[0];  // (4,256,512)
  const float* keys    = (const float*)d_in[1];  // (4,1024,512)
  const float* values  = (const float*)d_in[2];  // (4,1024,512)
  const float* Wq      = (const float*)d_in[3];  // (512,128)
  const float* Wk      = (const float*)d_in[4];  // (512,128)
  const float* wv      = (const float*)d_in[5];  // (128,)
  const int*   vlen    = (const int*)d_in[6];    // (4,)
  float* out = (float*)d_out;                    // (4,256,512)

  float* qh   = (float*)d_ws;                    // 4*256*128
  float* kh   = qh + (size_t)NB * NQ * NH;       // 4*1024*128
  float* attn = kh + (size_t)NB * NK * NH;       // 4*256*1024

  proj_kernel<<<(NB * NQ) / 8, 256, 0, stream>>>(queries, Wq, qh);
  proj_kernel<<<(NB * NK) / 8, 256, 0, stream>>>(keys, Wk, kh);
  scores_kernel<<<NB * 64 * 4, 256, 0, stream>>>(qh, kh, wv, vlen, attn);
  softmax_kernel<<<NB * NQ, 64, 0, stream>>>(attn);
  pv_kernel<<<NB * 32 * 4, 256, 0, stream>>>(attn, values, out);
}

// Round 3
// 156.154 us; speedup vs baseline: 1.4675x; 1.0125x over previous
//
#include <hip/hip_runtime.h>

#define NB 4
#define NQ 256
#define NK 1024
#define ND 512
#define NH 128

// ---------------------------------------------------------------------------
// Kernel 1: fused projections. Blocks [0,128): queries->qh, [128,640): keys->kh.
// Y[row,h] = sum_d X[row,d] * W[d,h]. 8 rows per block.
// ---------------------------------------------------------------------------
__global__ __launch_bounds__(256) void proj_all_kernel(
    const float* __restrict__ queries, const float* __restrict__ keys,
    const float* __restrict__ Wq, const float* __restrict__ Wk,
    float* __restrict__ qh, float* __restrict__ kh) {
  __shared__ float xs[8][ND];
  const int bid = blockIdx.x;
  const float *X, *W;
  float* Y;
  int row0;
  if (bid < 128) { X = queries; W = Wq; Y = qh; row0 = bid * 8; }
  else           { X = keys;    W = Wk; Y = kh; row0 = (bid - 128) * 8; }
  {
    const float4* src = (const float4*)(X + (size_t)row0 * ND);
    float4* dst = (float4*)&xs[0][0];
    for (int i = threadIdx.x; i < 8 * ND / 4; i += 256) dst[i] = src[i];
  }
  __syncthreads();
  const int h = threadIdx.x & (NH - 1);
  const int r0 = (threadIdx.x >> 7) * 4;  // 0 or 4
  float acc0 = 0.f, acc1 = 0.f, acc2 = 0.f, acc3 = 0.f;
  for (int d = 0; d < ND; d += 4) {
    const float w0 = W[(d + 0) * NH + h];
    const float w1 = W[(d + 1) * NH + h];
    const float w2 = W[(d + 2) * NH + h];
    const float w3 = W[(d + 3) * NH + h];
    const float4 x0 = *(const float4*)&xs[r0 + 0][d];
    const float4 x1 = *(const float4*)&xs[r0 + 1][d];
    const float4 x2 = *(const float4*)&xs[r0 + 2][d];
    const float4 x3 = *(const float4*)&xs[r0 + 3][d];
    acc0 += x0.x * w0 + x0.y * w1 + x0.z * w2 + x0.w * w3;
    acc1 += x1.x * w0 + x1.y * w1 + x1.z * w2 + x1.w * w3;
    acc2 += x2.x * w0 + x2.y * w1 + x2.z * w2 + x2.w * w3;
    acc3 += x3.x * w0 + x3.y * w1 + x3.z * w2 + x3.w * w3;
  }
  Y[(size_t)(row0 + r0 + 0) * NH + h] = acc0;
  Y[(size_t)(row0 + r0 + 1) * NH + h] = acc1;
  Y[(size_t)(row0 + r0 + 2) * NH + h] = acc2;
  Y[(size_t)(row0 + r0 + 3) * NH + h] = acc3;
}

// ---------------------------------------------------------------------------
// Kernel 2: raw masked scores. Block = (b, 4 q-rows, 256-k chunk), grid 1024.
// Fully-masked chunks (kc*256 >= valid_len) write zeros and exit (ref
// semantics: masked logits are 0, not -inf).
// ---------------------------------------------------------------------------
__device__ __forceinline__ float fast_tanh(float x) {
  const float e = __builtin_exp2f(2.8853900817779268f * x);
  return 1.0f - 2.0f * __builtin_amdgcn_rcpf(e + 1.0f);
}

__global__ __launch_bounds__(256) void scores_kernel(
    const float* __restrict__ qh, const float* __restrict__ kh,
    const float* __restrict__ wv, const int* __restrict__ vlen,
    float* __restrict__ attn) {
  constexpr int TQ = 4;
  constexpr int KC = 256;
  constexpr int KT = 64;
  constexpr int KS = NH + 4;
  __shared__ float qs[TQ][NH];
  __shared__ float wvs[NH];
  __shared__ float khs[KT][KS];

  const int bid = blockIdx.x;
  const int kc = bid & 3;
  const int qt = (bid >> 2) & 63;
  const int b = bid >> 8;
  const int q0 = qt * TQ;
  const int t = threadIdx.x;
  const int vl = vlen[b];

  if (kc * KC >= vl) {  // fully masked chunk: zeros, no tanh work
    const int r = t >> 6, c = (t & 63) * 4;
    *(float4*)(attn + (size_t)(b * NQ + q0 + r) * NK + kc * KC + c) =
        make_float4(0.f, 0.f, 0.f, 0.f);
    return;
  }

  if (t < TQ * NH / 4) {
    const int r = t >> 5, c = t & 31;
    ((float4*)&qs[r][0])[c] =
        ((const float4*)(qh + (size_t)(b * NQ + q0 + r) * NH))[c];
  }
  if (t >= 224) ((float4*)wvs)[t - 224] = ((const float4*)wv)[t - 224];

  const int myk = t & 63;
  const int myq = t >> 6;

  for (int s0 = 0; s0 < KC; s0 += KT) {
    __syncthreads();
    {
      const float4* src =
          (const float4*)(kh + (size_t)(b * NK + kc * KC + s0) * NH);
      for (int i = t; i < KT * NH / 4; i += 256) {
        const int r = i >> 5, c = i & 31;
        *(float4*)&khs[r][c * 4] = src[i];
      }
    }
    __syncthreads();
    const int k = kc * KC + s0 + myk;
    float s = 0.f;
    #pragma unroll 8
    for (int h = 0; h < NH; h += 4) {
      const float4 kv = *(const float4*)&khs[myk][h];
      const float4 qv = *(const float4*)&qs[myq][h];
      const float4 w4 = *(const float4*)&wvs[h];
      s += w4.x * fast_tanh(qv.x + kv.x);
      s += w4.y * fast_tanh(qv.y + kv.y);
      s += w4.z * fast_tanh(qv.z + kv.z);
      s += w4.w * fast_tanh(qv.w + kv.w);
    }
    attn[(size_t)(b * NQ + q0 + myq) * NK + k] = (k < vl) ? s : 0.0f;
  }
}

// ---------------------------------------------------------------------------
// Kernel 3: in-place softmax over each 1024-long row. One wave per row.
// ---------------------------------------------------------------------------
__global__ __launch_bounds__(64) void softmax_kernel(float* __restrict__ attn) {
  const int row = blockIdx.x;
  float4* a = (float4*)(attn + (size_t)row * NK);
  const int lane = threadIdx.x;
  float4 v[4];
  #pragma unroll
  for (int j = 0; j < 4; ++j) v[j] = a[lane + 64 * j];
  float m = -1e30f;
  #pragma unroll
  for (int j = 0; j < 4; ++j)
    m = fmaxf(m, fmaxf(fmaxf(v[j].x, v[j].y), fmaxf(v[j].z, v[j].w)));
  #pragma unroll
  for (int off = 32; off; off >>= 1) m = fmaxf(m, __shfl_xor(m, off));
  const float c = 1.4426950408889634f;
  float sum = 0.f;
  #pragma unroll
  for (int j = 0; j < 4; ++j) {
    v[j].x = __builtin_exp2f(c * (v[j].x - m));
    v[j].y = __builtin_exp2f(c * (v[j].y - m));
    v[j].z = __builtin_exp2f(c * (v[j].z - m));
    v[j].w = __builtin_exp2f(c * (v[j].w - m));
    sum += v[j].x + v[j].y + v[j].z + v[j].w;
  }
  #pragma unroll
  for (int off = 32; off; off >>= 1) sum += __shfl_xor(sum, off);
  const float inv = 1.0f / sum;
  #pragma unroll
  for (int j = 0; j < 4; ++j) {
    v[j].x *= inv; v[j].y *= inv; v[j].z *= inv; v[j].w *= inv;
    a[lane + 64 * j] = v[j];
  }
}

// ---------------------------------------------------------------------------
// Kernel 4: k-split PV. Block = (b, 8 q, 128 d, 256-k chunk); grid 2048
// (8 blocks/CU -> 32 waves/CU). Partials atomicAdd'ed into out (pre-zeroed).
// ---------------------------------------------------------------------------
__global__ __launch_bounds__(256, 8) void pv_kernel(
    const float* __restrict__ attn, const float* __restrict__ values,
    float* __restrict__ out) {
  constexpr int TQ = 8, TD = 128, KC = 256;
  __shared__ float als[TQ][KC];  // 8 KB
  const int bid = blockIdx.x;
  const int kc = bid & 3;
  const int dt = (bid >> 2) & 3;
  const int qt = (bid >> 4) & 31;
  const int b = bid >> 9;
  const int q0 = qt * TQ;
  const int d0 = dt * TD;
  const int k0 = kc * KC;
  const int t = threadIdx.x;
  const int dl = t & 31;
  const int qg = t >> 5;

  {
    #pragma unroll
    for (int i = t; i < TQ * KC / 4; i += 256) {
      const int row = i >> 6, col = (i & 63) * 4;
      *(float4*)&als[row][col] =
          *(const float4*)(attn + (size_t)(b * NQ + q0 + row) * NK + k0 + col);
    }
  }
  __syncthreads();

  float4 acc = make_float4(0.f, 0.f, 0.f, 0.f);
  const float* vbase = values + (size_t)b * NK * ND + (size_t)k0 * ND + d0 + dl * 4;

  #pragma unroll 2
  for (int k = 0; k < KC; k += 4) {
    const float4 a4 = *(const float4*)&als[qg][k];
    const float4 v0 = *(const float4*)(vbase + (size_t)(k + 0) * ND);
    const float4 v1 = *(const float4*)(vbase + (size_t)(k + 1) * ND);
    const float4 v2 = *(const float4*)(vbase + (size_t)(k + 2) * ND);
    const float4 v3 = *(const float4*)(vbase + (size_t)(k + 3) * ND);
    acc.x += a4.x * v0.x + a4.y * v1.x + a4.z * v2.x + a4.w * v3.x;
    acc.y += a4.x * v0.y + a4.y * v1.y + a4.z * v2.y + a4.w * v3.y;
    acc.z += a4.x * v0.z + a4.y * v1.z + a4.z * v2.z + a4.w * v3.z;
    acc.w += a4.x * v0.w + a4.y * v1.w + a4.z * v2.w + a4.w * v3.w;
  }
  float* o = out + (size_t)(b * NQ + q0 + qg) * ND + d0 + dl * 4;
  atomicAdd(o + 0, acc.x);
  atomicAdd(o + 1, acc.y);
  atomicAdd(o + 2, acc.z);
  atomicAdd(o + 3, acc.w);
}

// ---------------------------------------------------------------------------
extern "C" void kernel_launch(void* const* d_in, const int* in_sizes, int n_in,
                              void* d_out, int out_size, void* d_ws, size_t ws_size,
                              hipStream_t stream) {
  const float* queries = (const float*)d_in[0];
  const float* keys    = (const float*)d_in[1];
  const float* values  = (const float*)d_in[2];
  const float* Wq      = (const float*)d_in[3];
  const float* Wk      = (const float*)d_in[4];
  const float* wv      = (const float*)d_in[5];
  const int*   vlen    = (const int*)d_in[6];
  float* out = (float*)d_out;

  float* qh   = (float*)d_ws;
  float* kh   = qh + (size_t)NB * NQ * NH;
  float* attn = kh + (size_t)NB * NK * NH;

  proj_all_kernel<<<640, 256, 0, stream>>>(queries, keys, Wq, Wk, qh, kh);
  scores_kernel<<<NB * 64 * 4, 256, 0, stream>>>(qh, kh, wv, vlen, attn);
  softmax_kernel<<<NB * NQ, 64, 0, stream>>>(attn);
  hipMemsetAsync(d_out, 0, (size_t)out_size * sizeof(float), stream);
  pv_kernel<<<NB * 32 * 4 * 4, 256, 0, stream>>>(attn, values, out);
}

// Round 4
// 110.949 us; speedup vs baseline: 2.0655x; 1.4074x over previous
//
#include <hip/hip_runtime.h>

#define NB 4
#define NQ 256
#define NK 1024
#define ND 512
#define NH 128

typedef _Float16 half8_t __attribute__((ext_vector_type(8)));
typedef _Float16 half4_t __attribute__((ext_vector_type(4)));
typedef float f32x4_t __attribute__((ext_vector_type(4)));

#define TANH_C 2.8853900817779268f  // 2*log2(e): tanh(x)=1-2/(exp2(C*x)+1)

// ---------------------------------------------------------------------------
// Kernel 1: fused projections + exp2. Blocks [0,128): queries -> EQ,
// [128,640): keys -> EK.  E*[row,h] = exp2(C * sum_d X[row,d]*W[d,h]).
// ---------------------------------------------------------------------------
__global__ __launch_bounds__(256) void proj_exp_kernel(
    const float* __restrict__ queries, const float* __restrict__ keys,
    const float* __restrict__ Wq, const float* __restrict__ Wk,
    float* __restrict__ EQ, float* __restrict__ EK) {
  __shared__ float xs[8][ND];
  const int bid = blockIdx.x;
  const float *X, *W;
  float* Y;
  int row0;
  if (bid < 128) { X = queries; W = Wq; Y = EQ; row0 = bid * 8; }
  else           { X = keys;    W = Wk; Y = EK; row0 = (bid - 128) * 8; }
  {
    const float4* src = (const float4*)(X + (size_t)row0 * ND);
    float4* dst = (float4*)&xs[0][0];
    for (int i = threadIdx.x; i < 8 * ND / 4; i += 256) dst[i] = src[i];
  }
  __syncthreads();
  const int h = threadIdx.x & (NH - 1);
  const int r0 = (threadIdx.x >> 7) * 4;  // 0 or 4
  float acc0 = 0.f, acc1 = 0.f, acc2 = 0.f, acc3 = 0.f;
  for (int d = 0; d < ND; d += 4) {
    const float w0 = W[(d + 0) * NH + h];
    const float w1 = W[(d + 1) * NH + h];
    const float w2 = W[(d + 2) * NH + h];
    const float w3 = W[(d + 3) * NH + h];
    const float4 x0 = *(const float4*)&xs[r0 + 0][d];
    const float4 x1 = *(const float4*)&xs[r0 + 1][d];
    const float4 x2 = *(const float4*)&xs[r0 + 2][d];
    const float4 x3 = *(const float4*)&xs[r0 + 3][d];
    acc0 += x0.x * w0 + x0.y * w1 + x0.z * w2 + x0.w * w3;
    acc1 += x1.x * w0 + x1.y * w1 + x1.z * w2 + x1.w * w3;
    acc2 += x2.x * w0 + x2.y * w1 + x2.z * w2 + x2.w * w3;
    acc3 += x3.x * w0 + x3.y * w1 + x3.z * w2 + x3.w * w3;
  }
  Y[(size_t)(row0 + r0 + 0) * NH + h] = __builtin_exp2f(TANH_C * acc0);
  Y[(size_t)(row0 + r0 + 1) * NH + h] = __builtin_exp2f(TANH_C * acc1);
  Y[(size_t)(row0 + r0 + 2) * NH + h] = __builtin_exp2f(TANH_C * acc2);
  Y[(size_t)(row0 + r0 + 3) * NH + h] = __builtin_exp2f(TANH_C * acc3);
}

// ---------------------------------------------------------------------------
// Kernel 2: scores via precomputed exponentials — NO exp in the inner loop.
// s(q,k) = sum_h wv[h]*tanh(qh+kh) = Wsum - 2*sum_h wv[h]/(EQ[q,h]*EK[k,h]+1)
// Block = (b, 4 q-rows, 256-k chunk), grid 1024, 4 waves (wave = q-row),
// lane = k within 64-subtile, 4 subtiles. Masked logits -> 0 (ref semantics).
// ---------------------------------------------------------------------------
__global__ __launch_bounds__(256) void scores_kernel(
    const float* __restrict__ EQ, const float* __restrict__ EK,
    const float* __restrict__ wv, const int* __restrict__ vlen,
    float* __restrict__ scores) {
  constexpr int TQ = 4, KC = 256;
  __shared__ float eqs[TQ][NH];
  __shared__ float wvs[NH];

  const int bid = blockIdx.x;
  const int kc = bid & 3;
  const int qt = (bid >> 2) & 63;
  const int b = bid >> 8;
  const int q0 = qt * TQ;
  const int t = threadIdx.x;
  const int vl = vlen[b];

  if (kc * KC >= vl) {  // fully masked chunk: zeros, no work
    const int r = t >> 6, c = (t & 63) * 4;
    *(float4*)(scores + (size_t)(b * NQ + q0 + r) * NK + kc * KC + c) =
        make_float4(0.f, 0.f, 0.f, 0.f);
    return;
  }

  for (int i = t; i < TQ * NH; i += 256)
    eqs[i >> 7][i & (NH - 1)] =
        EQ[(size_t)(b * NQ + q0 + (i >> 7)) * NH + (i & (NH - 1))];
  if (t < 32) ((float4*)wvs)[t] = ((const float4*)wv)[t];
  __syncthreads();

  const int myq = t >> 6;
  const int l = t & 63;

  // Wsum = sum_h wv[h] (wave-redundant shuffle reduce)
  float Wsum = wvs[l] + wvs[l + 64];
  #pragma unroll
  for (int off = 32; off; off >>= 1) Wsum += __shfl_xor(Wsum, off);

  const size_t ekbase = ((size_t)b * NK + kc * KC + l) * NH;
  const float4* ek0 = (const float4*)(EK + ekbase + 0 * 64 * NH);
  const float4* ek1 = (const float4*)(EK + ekbase + 1 * 64 * NH);
  const float4* ek2 = (const float4*)(EK + ekbase + 2 * 64 * NH);
  const float4* ek3 = (const float4*)(EK + ekbase + 3 * 64 * NH);

  float acc0 = 0.f, acc1 = 0.f, acc2 = 0.f, acc3 = 0.f;
  #pragma unroll 2
  for (int hc = 0; hc < 8; ++hc) {  // 16 h per chunk
    float4 q4[4], w4[4];
    #pragma unroll
    for (int j = 0; j < 4; ++j) {
      q4[j] = *(const float4*)&eqs[myq][hc * 16 + j * 4];
      w4[j] = *(const float4*)&wvs[hc * 16 + j * 4];
    }
    #pragma unroll
    for (int j = 0; j < 4; ++j) {
      const int ei = hc * 4 + j;
      float4 e;
      e = ek0[ei];
      acc0 = fmaf(w4[j].x, __builtin_amdgcn_rcpf(fmaf(q4[j].x, e.x, 1.f)), acc0);
      acc0 = fmaf(w4[j].y, __builtin_amdgcn_rcpf(fmaf(q4[j].y, e.y, 1.f)), acc0);
      acc0 = fmaf(w4[j].z, __builtin_amdgcn_rcpf(fmaf(q4[j].z, e.z, 1.f)), acc0);
      acc0 = fmaf(w4[j].w, __builtin_amdgcn_rcpf(fmaf(q4[j].w, e.w, 1.f)), acc0);
      e = ek1[ei];
      acc1 = fmaf(w4[j].x, __builtin_amdgcn_rcpf(fmaf(q4[j].x, e.x, 1.f)), acc1);
      acc1 = fmaf(w4[j].y, __builtin_amdgcn_rcpf(fmaf(q4[j].y, e.y, 1.f)), acc1);
      acc1 = fmaf(w4[j].z, __builtin_amdgcn_rcpf(fmaf(q4[j].z, e.z, 1.f)), acc1);
      acc1 = fmaf(w4[j].w, __builtin_amdgcn_rcpf(fmaf(q4[j].w, e.w, 1.f)), acc1);
      e = ek2[ei];
      acc2 = fmaf(w4[j].x, __builtin_amdgcn_rcpf(fmaf(q4[j].x, e.x, 1.f)), acc2);
      acc2 = fmaf(w4[j].y, __builtin_amdgcn_rcpf(fmaf(q4[j].y, e.y, 1.f)), acc2);
      acc2 = fmaf(w4[j].z, __builtin_amdgcn_rcpf(fmaf(q4[j].z, e.z, 1.f)), acc2);
      acc2 = fmaf(w4[j].w, __builtin_amdgcn_rcpf(fmaf(q4[j].w, e.w, 1.f)), acc2);
      e = ek3[ei];
      acc3 = fmaf(w4[j].x, __builtin_amdgcn_rcpf(fmaf(q4[j].x, e.x, 1.f)), acc3);
      acc3 = fmaf(w4[j].y, __builtin_amdgcn_rcpf(fmaf(q4[j].y, e.y, 1.f)), acc3);
      acc3 = fmaf(w4[j].z, __builtin_amdgcn_rcpf(fmaf(q4[j].z, e.z, 1.f)), acc3);
      acc3 = fmaf(w4[j].w, __builtin_amdgcn_rcpf(fmaf(q4[j].w, e.w, 1.f)), acc3);
    }
  }

  float* srow = scores + (size_t)(b * NQ + q0 + myq) * NK + kc * KC;
  const int k0 = kc * KC;
  srow[0 * 64 + l] = (k0 + 0 * 64 + l < vl) ? (Wsum - 2.f * acc0) : 0.f;
  srow[1 * 64 + l] = (k0 + 1 * 64 + l < vl) ? (Wsum - 2.f * acc1) : 0.f;
  srow[2 * 64 + l] = (k0 + 2 * 64 + l < vl) ? (Wsum - 2.f * acc2) : 0.f;
  srow[3 * 64 + l] = (k0 + 3 * 64 + l < vl) ? (Wsum - 2.f * acc3) : 0.f;
}

// ---------------------------------------------------------------------------
// Kernel 3: softmax over each 1024 row of scores -> fp16 attn. One wave/row.
// ---------------------------------------------------------------------------
__global__ __launch_bounds__(64) void softmax_kernel(
    const float* __restrict__ scores, _Float16* __restrict__ attn_h) {
  const int row = blockIdx.x;
  const float4* a = (const float4*)(scores + (size_t)row * NK);
  const int lane = threadIdx.x;
  float4 v[4];
  #pragma unroll
  for (int j = 0; j < 4; ++j) v[j] = a[lane + 64 * j];
  float m = -1e30f;
  #pragma unroll
  for (int j = 0; j < 4; ++j)
    m = fmaxf(m, fmaxf(fmaxf(v[j].x, v[j].y), fmaxf(v[j].z, v[j].w)));
  #pragma unroll
  for (int off = 32; off; off >>= 1) m = fmaxf(m, __shfl_xor(m, off));
  const float c = 1.4426950408889634f;
  float sum = 0.f;
  #pragma unroll
  for (int j = 0; j < 4; ++j) {
    v[j].x = __builtin_exp2f(c * (v[j].x - m));
    v[j].y = __builtin_exp2f(c * (v[j].y - m));
    v[j].z = __builtin_exp2f(c * (v[j].z - m));
    v[j].w = __builtin_exp2f(c * (v[j].w - m));
    sum += v[j].x + v[j].y + v[j].z + v[j].w;
  }
  #pragma unroll
  for (int off = 32; off; off >>= 1) sum += __shfl_xor(sum, off);
  const float inv = 1.0f / sum;
  _Float16* orow = attn_h + (size_t)row * NK;
  #pragma unroll
  for (int j = 0; j < 4; ++j) {
    half4_t h;
    h[0] = (_Float16)(v[j].x * inv);
    h[1] = (_Float16)(v[j].y * inv);
    h[2] = (_Float16)(v[j].z * inv);
    h[3] = (_Float16)(v[j].w * inv);
    *(half4_t*)(orow + 256 * j + lane * 4) = h;
  }
}

// ---------------------------------------------------------------------------
// Kernel 4: transpose+convert values (B,K,D) fp32 -> vT (B,D,K) fp16.
// 64x64 tiles via LDS. Grid = 4 * 16 * 8 = 512.
// ---------------------------------------------------------------------------
__global__ __launch_bounds__(256) void vt_convert_kernel(
    const float* __restrict__ values, _Float16* __restrict__ vT) {
  __shared__ float tile[64][65];
  const int bid = blockIdx.x;
  const int dt = bid & 7;
  const int kt = (bid >> 3) & 15;
  const int b = bid >> 7;
  const int k0 = kt * 64, d0 = dt * 64;
  const int t = threadIdx.x;
  {
    const int kl = t >> 4, dl4 = (t & 15) * 4;
    #pragma unroll
    for (int i = 0; i < 4; ++i) {
      const float4 v = *(const float4*)(
          values + ((size_t)(b * NK + k0 + kl + i * 16)) * ND + d0 + dl4);
      tile[dl4 + 0][kl + i * 16] = v.x;
      tile[dl4 + 1][kl + i * 16] = v.y;
      tile[dl4 + 2][kl + i * 16] = v.z;
      tile[dl4 + 3][kl + i * 16] = v.w;
    }
  }
  __syncthreads();
  const int dr = t >> 2, kc = (t & 3) * 16;
  half8_t h0, h1;
  #pragma unroll
  for (int ii = 0; ii < 8; ++ii) {
    h0[ii] = (_Float16)tile[dr][kc + ii];
    h1[ii] = (_Float16)tile[dr][kc + 8 + ii];
  }
  _Float16* dst = vT + ((size_t)(b * ND + d0 + dr)) * NK + k0 + kc;
  *(half8_t*)dst = h0;
  *(half8_t*)(dst + 8) = h1;
}

// ---------------------------------------------------------------------------
// Kernel 5: PV via MFMA fp16.  out[b,q,d] = sum_k attn[q,k]*vT[d,k].
// Tile 32q x 64d per block, grid 4*8*8 = 256, 4 waves, wave = 16x32 (2 frags).
// A/B fragments read directly from global (L2-resident), 16B contiguous in k.
// mfma_f32_16x16x32_f16: lane l holds A[m=l&15][k=(l>>4)*8+j]; D: n=l&15,
// m=(l>>4)*4+r (verified layout, learn_hip m89).
// ---------------------------------------------------------------------------
__global__ __launch_bounds__(256) void pv_mfma_kernel(
    const _Float16* __restrict__ attn_h, const _Float16* __restrict__ vT,
    float* __restrict__ out) {
  const int bid = blockIdx.x;
  const int nt8 = bid & 7;         // 64-d block
  const int mt = (bid >> 3) & 7;   // 32-q block
  const int b = bid >> 6;
  const int w = threadIdx.x >> 6;
  const int l = threadIdx.x & 63;
  const int mtile = w & 1;
  const int ntile0 = (w >> 1) * 2;
  const int q_lo = mt * 32 + mtile * 16;
  const int d_lo = nt8 * 64 + ntile0 * 16;

  const _Float16* arow =
      attn_h + ((size_t)(b * NQ + q_lo + (l & 15))) * NK + (l >> 4) * 8;
  const _Float16* brow0 =
      vT + ((size_t)(b * ND + d_lo + (l & 15))) * NK + (l >> 4) * 8;
  const _Float16* brow1 = brow0 + 16 * NK;

  f32x4_t acc0 = {0.f, 0.f, 0.f, 0.f};
  f32x4_t acc1 = {0.f, 0.f, 0.f, 0.f};
  #pragma unroll 4
  for (int ks = 0; ks < NK; ks += 32) {
    const half8_t a  = *(const half8_t*)(arow + ks);
    const half8_t b0 = *(const half8_t*)(brow0 + ks);
    const half8_t b1 = *(const half8_t*)(brow1 + ks);
    acc0 = __builtin_amdgcn_mfma_f32_16x16x32_f16(a, b0, acc0, 0, 0, 0);
    acc1 = __builtin_amdgcn_mfma_f32_16x16x32_f16(a, b1, acc1, 0, 0, 0);
  }
  const int mrow = q_lo + (l >> 4) * 4;
  const int dcol = d_lo + (l & 15);
  #pragma unroll
  for (int r = 0; r < 4; ++r) {
    out[(size_t)(b * NQ + mrow + r) * ND + dcol] = acc0[r];
    out[(size_t)(b * NQ + mrow + r) * ND + dcol + 16] = acc1[r];
  }
}

// ---------------------------------------------------------------------------
extern "C" void kernel_launch(void* const* d_in, const int* in_sizes, int n_in,
                              void* d_out, int out_size, void* d_ws, size_t ws_size,
                              hipStream_t stream) {
  const float* queries = (const float*)d_in[0];
  const float* keys    = (const float*)d_in[1];
  const float* values  = (const float*)d_in[2];
  const float* Wq      = (const float*)d_in[3];
  const float* Wk      = (const float*)d_in[4];
  const float* wv      = (const float*)d_in[5];
  const int*   vlen    = (const int*)d_in[6];
  float* out = (float*)d_out;

  // ws layout (floats) — peak 6.5 MB via overlays:
  //   EQ [0, 131072) | EK [131072, 655360) | scores [655360, 1703936)
  //   attn_h overlays EK (dead after scores_kernel)
  //   vT overlays scores (dead after softmax_kernel)
  float* EQ = (float*)d_ws;
  float* EK = EQ + (size_t)NB * NQ * NH;
  float* scores = EK + (size_t)NB * NK * NH;
  _Float16* attn_h = (_Float16*)EK;
  _Float16* vT = (_Float16*)scores;

  proj_exp_kernel<<<640, 256, 0, stream>>>(queries, keys, Wq, Wk, EQ, EK);
  scores_kernel<<<NB * 64 * 4, 256, 0, stream>>>(EQ, EK, wv, vlen, scores);
  softmax_kernel<<<NB * NQ, 64, 0, stream>>>(scores, attn_h);
  vt_convert_kernel<<<512, 256, 0, stream>>>(values, vT);
  pv_mfma_kernel<<<NB * 8 * 8, 256, 0, stream>>>(attn_h, vT, out);
}

// Round 5
// 77.736 us; speedup vs baseline: 2.9480x; 1.4273x over previous
//
#include <hip/hip_runtime.h>

#define NB 4
#define NQ 256
#define NK 1024
#define ND 512
#define NH 128

typedef _Float16 half8_t __attribute__((ext_vector_type(8)));
typedef _Float16 half4_t __attribute__((ext_vector_type(4)));
typedef float f32x4_t __attribute__((ext_vector_type(4)));

#define TANH_C 2.8853900817779268f  // 2*log2(e): tanh(x)=1-2/(exp2(C*x)+1)

// ---------------------------------------------------------------------------
// Kernel 1: fused projections + exp2. Blocks [0,128): queries -> EQ,
// [128,640): keys -> EK.  E*[row,h] = exp2(C * sum_d X[row,d]*W[d,h]).
// ---------------------------------------------------------------------------
__global__ __launch_bounds__(256) void proj_exp_kernel(
    const float* __restrict__ queries, const float* __restrict__ keys,
    const float* __restrict__ Wq, const float* __restrict__ Wk,
    float* __restrict__ EQ, float* __restrict__ EK) {
  __shared__ float xs[8][ND];
  const int bid = blockIdx.x;
  const float *X, *W;
  float* Y;
  int row0;
  if (bid < 128) { X = queries; W = Wq; Y = EQ; row0 = bid * 8; }
  else           { X = keys;    W = Wk; Y = EK; row0 = (bid - 128) * 8; }
  {
    const float4* src = (const float4*)(X + (size_t)row0 * ND);
    float4* dst = (float4*)&xs[0][0];
    for (int i = threadIdx.x; i < 8 * ND / 4; i += 256) dst[i] = src[i];
  }
  __syncthreads();
  const int h = threadIdx.x & (NH - 1);
  const int r0 = (threadIdx.x >> 7) * 4;  // 0 or 4
  float acc0 = 0.f, acc1 = 0.f, acc2 = 0.f, acc3 = 0.f;
  for (int d = 0; d < ND; d += 4) {
    const float w0 = W[(d + 0) * NH + h];
    const float w1 = W[(d + 1) * NH + h];
    const float w2 = W[(d + 2) * NH + h];
    const float w3 = W[(d + 3) * NH + h];
    const float4 x0 = *(const float4*)&xs[r0 + 0][d];
    const float4 x1 = *(const float4*)&xs[r0 + 1][d];
    const float4 x2 = *(const float4*)&xs[r0 + 2][d];
    const float4 x3 = *(const float4*)&xs[r0 + 3][d];
    acc0 += x0.x * w0 + x0.y * w1 + x0.z * w2 + x0.w * w3;
    acc1 += x1.x * w0 + x1.y * w1 + x1.z * w2 + x1.w * w3;
    acc2 += x2.x * w0 + x2.y * w1 + x2.z * w2 + x2.w * w3;
    acc3 += x3.x * w0 + x3.y * w1 + x3.z * w2 + x3.w * w3;
  }
  Y[(size_t)(row0 + r0 + 0) * NH + h] = __builtin_exp2f(TANH_C * acc0);
  Y[(size_t)(row0 + r0 + 1) * NH + h] = __builtin_exp2f(TANH_C * acc1);
  Y[(size_t)(row0 + r0 + 2) * NH + h] = __builtin_exp2f(TANH_C * acc2);
  Y[(size_t)(row0 + r0 + 3) * NH + h] = __builtin_exp2f(TANH_C * acc3);
}

// ---------------------------------------------------------------------------
// Kernel 2: scores = Wsum - 2*sum_h wv[h]/(EQ[q,h]*EK[k,h]+1).  No exp.
// Block = (b, 4 q-rows, 256-k chunk). EK chunks (64 rows x 128 f) staged in
// LDS coalesced, stored XOR-swizzled so lane-l-reads-row-l is conflict-free:
//   float4 index = row*32 + (slot ^ (row&7)).
// eqs/wvs reads are lane-uniform (broadcast, free). Wave = q-row, lane = k.
// ---------------------------------------------------------------------------
__global__ __launch_bounds__(256) void scores_kernel(
    const float* __restrict__ EQ, const float* __restrict__ EK,
    const float* __restrict__ wv, const int* __restrict__ vlen,
    float* __restrict__ scores) {
  constexpr int TQ = 4, KC = 256, KT = 64;
  __shared__ float eqs[TQ][NH];
  __shared__ float wvs[NH];
  __shared__ float khs[KT * NH];  // 32 KB, XOR-swizzled float4 layout

  const int bid = blockIdx.x;
  const int kc = bid & 3;
  const int qt = (bid >> 2) & 63;
  const int b = bid >> 8;
  const int q0 = qt * TQ;
  const int t = threadIdx.x;
  const int vl = vlen[b];

  if (kc * KC >= vl) {  // fully masked chunk: zeros, no work
    const int r = t >> 6, c = (t & 63) * 4;
    *(float4*)(scores + (size_t)(b * NQ + q0 + r) * NK + kc * KC + c) =
        make_float4(0.f, 0.f, 0.f, 0.f);
    return;
  }

  if (t < TQ * NH / 4) {
    const int r = t >> 5, c = t & 31;
    ((float4*)&eqs[r][0])[c] =
        ((const float4*)(EQ + (size_t)(b * NQ + q0 + r) * NH))[c];
  }
  if (t >= 224) ((float4*)wvs)[t - 224] = ((const float4*)wv)[t - 224];
  __syncthreads();

  const int myq = t >> 6;
  const int l = t & 63;

  // Wsum = sum_h wv[h] (wave-redundant shuffle reduce)
  float Wsum = wvs[l] + wvs[l + 64];
  #pragma unroll
  for (int off = 32; off; off >>= 1) Wsum += __shfl_xor(Wsum, off);

  float4* khs4 = (float4*)khs;
  const float4* eq4 = (const float4*)&eqs[myq][0];
  const float4* wv4 = (const float4*)wvs;

  for (int c0 = 0; c0 < KC; c0 += KT) {
    __syncthreads();
    {  // coalesced stage of 64 rows x 128 floats, swizzled store
      const float4* src =
          (const float4*)(EK + ((size_t)b * NK + kc * KC + c0) * NH);
      #pragma unroll
      for (int i = 0; i < 8; ++i) {
        const int idx = t + i * 256;
        const int row = idx >> 5, slot = idx & 31;
        khs4[row * 32 + (slot ^ (row & 7))] = src[idx];
      }
    }
    __syncthreads();
    float acc = 0.f;
    const int lbase = l * 32;
    const int lx = l & 7;
    #pragma unroll
    for (int slot = 0; slot < 32; ++slot) {
      const float4 e = khs4[lbase + (slot ^ lx)];
      const float4 q4 = eq4[slot];
      const float4 w4 = wv4[slot];
      acc = fmaf(w4.x, __builtin_amdgcn_rcpf(fmaf(q4.x, e.x, 1.f)), acc);
      acc = fmaf(w4.y, __builtin_amdgcn_rcpf(fmaf(q4.y, e.y, 1.f)), acc);
      acc = fmaf(w4.z, __builtin_amdgcn_rcpf(fmaf(q4.z, e.z, 1.f)), acc);
      acc = fmaf(w4.w, __builtin_amdgcn_rcpf(fmaf(q4.w, e.w, 1.f)), acc);
    }
    const int k = kc * KC + c0 + l;
    scores[(size_t)(b * NQ + q0 + myq) * NK + k] =
        (k < vl) ? (Wsum - 2.f * acc) : 0.f;
  }
}

// ---------------------------------------------------------------------------
// Kernel 3: softmax over each 1024 row of scores -> fp16 attn. One wave/row.
// ---------------------------------------------------------------------------
__global__ __launch_bounds__(64) void softmax_kernel(
    const float* __restrict__ scores, _Float16* __restrict__ attn_h) {
  const int row = blockIdx.x;
  const float4* a = (const float4*)(scores + (size_t)row * NK);
  const int lane = threadIdx.x;
  float4 v[4];
  #pragma unroll
  for (int j = 0; j < 4; ++j) v[j] = a[lane + 64 * j];
  float m = -1e30f;
  #pragma unroll
  for (int j = 0; j < 4; ++j)
    m = fmaxf(m, fmaxf(fmaxf(v[j].x, v[j].y), fmaxf(v[j].z, v[j].w)));
  #pragma unroll
  for (int off = 32; off; off >>= 1) m = fmaxf(m, __shfl_xor(m, off));
  const float c = 1.4426950408889634f;
  float sum = 0.f;
  #pragma unroll
  for (int j = 0; j < 4; ++j) {
    v[j].x = __builtin_exp2f(c * (v[j].x - m));
    v[j].y = __builtin_exp2f(c * (v[j].y - m));
    v[j].z = __builtin_exp2f(c * (v[j].z - m));
    v[j].w = __builtin_exp2f(c * (v[j].w - m));
    sum += v[j].x + v[j].y + v[j].z + v[j].w;
  }
  #pragma unroll
  for (int off = 32; off; off >>= 1) sum += __shfl_xor(sum, off);
  const float inv = 1.0f / sum;
  _Float16* orow = attn_h + (size_t)row * NK;
  #pragma unroll
  for (int j = 0; j < 4; ++j) {
    half4_t h;
    h[0] = (_Float16)(v[j].x * inv);
    h[1] = (_Float16)(v[j].y * inv);
    h[2] = (_Float16)(v[j].z * inv);
    h[3] = (_Float16)(v[j].w * inv);
    *(half4_t*)(orow + 256 * j + lane * 4) = h;
  }
}

// ---------------------------------------------------------------------------
// Kernel 4: transpose+convert values (B,K,D) fp32 -> vT (B,D,K) fp16.
// ---------------------------------------------------------------------------
__global__ __launch_bounds__(256) void vt_convert_kernel(
    const float* __restrict__ values, _Float16* __restrict__ vT) {
  __shared__ float tile[64][65];
  const int bid = blockIdx.x;
  const int dt = bid & 7;
  const int kt = (bid >> 3) & 15;
  const int b = bid >> 7;
  const int k0 = kt * 64, d0 = dt * 64;
  const int t = threadIdx.x;
  {
    const int kl = t >> 4, dl4 = (t & 15) * 4;
    #pragma unroll
    for (int i = 0; i < 4; ++i) {
      const float4 v = *(const float4*)(
          values + ((size_t)(b * NK + k0 + kl + i * 16)) * ND + d0 + dl4);
      tile[dl4 + 0][kl + i * 16] = v.x;
      tile[dl4 + 1][kl + i * 16] = v.y;
      tile[dl4 + 2][kl + i * 16] = v.z;
      tile[dl4 + 3][kl + i * 16] = v.w;
    }
  }
  __syncthreads();
  const int dr = t >> 2, kc = (t & 3) * 16;
  half8_t h0, h1;
  #pragma unroll
  for (int ii = 0; ii < 8; ++ii) {
    h0[ii] = (_Float16)tile[dr][kc + ii];
    h1[ii] = (_Float16)tile[dr][kc + 8 + ii];
  }
  _Float16* dst = vT + ((size_t)(b * ND + d0 + dr)) * NK + k0 + kc;
  *(half8_t*)dst = h0;
  *(half8_t*)(dst + 8) = h1;
}

// ---------------------------------------------------------------------------
// Kernel 5: PV via MFMA fp16, k-split by 4 for occupancy (grid 1024, 4
// blocks/CU, 16 waves/CU). Partials atomicAdd'ed into pre-zeroed out.
// Wave = 16q x 32d (2 fragments), 8 k-steps of 32.
// ---------------------------------------------------------------------------
__global__ __launch_bounds__(256) void pv_mfma_kernel(
    const _Float16* __restrict__ attn_h, const _Float16* __restrict__ vT,
    float* __restrict__ out) {
  const int bid = blockIdx.x;
  const int kc  = bid & 3;         // 256-k chunk
  const int nt8 = (bid >> 2) & 7;  // 64-d block
  const int mt  = (bid >> 5) & 7;  // 32-q block
  const int b   = bid >> 8;
  const int w = threadIdx.x >> 6;
  const int l = threadIdx.x & 63;
  const int mtile = w & 1;
  const int ntile0 = (w >> 1) * 2;
  const int q_lo = mt * 32 + mtile * 16;
  const int d_lo = nt8 * 64 + ntile0 * 16;
  const int k0 = kc * 256;

  const _Float16* arow =
      attn_h + ((size_t)(b * NQ + q_lo + (l & 15))) * NK + k0 + (l >> 4) * 8;
  const _Float16* brow0 =
      vT + ((size_t)(b * ND + d_lo + (l & 15))) * NK + k0 + (l >> 4) * 8;
  const _Float16* brow1 = brow0 + 16 * NK;

  f32x4_t acc0 = {0.f, 0.f, 0.f, 0.f};
  f32x4_t acc1 = {0.f, 0.f, 0.f, 0.f};
  #pragma unroll
  for (int ks = 0; ks < 256; ks += 32) {
    const half8_t a  = *(const half8_t*)(arow + ks);
    const half8_t b0 = *(const half8_t*)(brow0 + ks);
    const half8_t b1 = *(const half8_t*)(brow1 + ks);
    acc0 = __builtin_amdgcn_mfma_f32_16x16x32_f16(a, b0, acc0, 0, 0, 0);
    acc1 = __builtin_amdgcn_mfma_f32_16x16x32_f16(a, b1, acc1, 0, 0, 0);
  }
  const int mrow = q_lo + (l >> 4) * 4;
  const int dcol = d_lo + (l & 15);
  #pragma unroll
  for (int r = 0; r < 4; ++r) {
    atomicAdd(&out[(size_t)(b * NQ + mrow + r) * ND + dcol], acc0[r]);
    atomicAdd(&out[(size_t)(b * NQ + mrow + r) * ND + dcol + 16], acc1[r]);
  }
}

// ---------------------------------------------------------------------------
extern "C" void kernel_launch(void* const* d_in, const int* in_sizes, int n_in,
                              void* d_out, int out_size, void* d_ws, size_t ws_size,
                              hipStream_t stream) {
  const float* queries = (const float*)d_in[0];
  const float* keys    = (const float*)d_in[1];
  const float* values  = (const float*)d_in[2];
  const float* Wq      = (const float*)d_in[3];
  const float* Wk      = (const float*)d_in[4];
  const float* wv      = (const float*)d_in[5];
  const int*   vlen    = (const int*)d_in[6];
  float* out = (float*)d_out;

  // ws overlays: attn_h over dead EK, vT over dead scores
  float* EQ = (float*)d_ws;
  float* EK = EQ + (size_t)NB * NQ * NH;
  float* scores = EK + (size_t)NB * NK * NH;
  _Float16* attn_h = (_Float16*)EK;
  _Float16* vT = (_Float16*)scores;

  proj_exp_kernel<<<640, 256, 0, stream>>>(queries, keys, Wq, Wk, EQ, EK);
  scores_kernel<<<NB * 64 * 4, 256, 0, stream>>>(EQ, EK, wv, vlen, scores);
  softmax_kernel<<<NB * NQ, 64, 0, stream>>>(scores, attn_h);
  vt_convert_kernel<<<512, 256, 0, stream>>>(values, vT);
  hipMemsetAsync(d_out, 0, (size_t)out_size * sizeof(float), stream);
  pv_mfma_kernel<<<NB * 8 * 8 * 4, 256, 0, stream>>>(attn_h, vT, out);
}

// Round 6
// 76.392 us; speedup vs baseline: 2.9998x; 1.0176x over previous
//
#include <hip/hip_runtime.h>

#define NB 4
#define NQ 256
#define NK 1024
#define ND 512
#define NH 128

typedef _Float16 half8_t __attribute__((ext_vector_type(8)));
typedef _Float16 half4_t __attribute__((ext_vector_type(4)));
typedef float f32x4_t __attribute__((ext_vector_type(4)));

#define TANH_C 2.8853900817779268f  // 2*log2(e): tanh(x)=1-2/(exp2(C*x)+1)

// ---------------------------------------------------------------------------
// Kernel 0: W (512,128) fp32 -> WT (128,512) fp16, for Wq and Wk.
// Grid 16: bid>>3 selects matrix, (bid&7)*64 = d-chunk. LDS transpose.
// ---------------------------------------------------------------------------
__global__ __launch_bounds__(256) void wt_convert_kernel(
    const float* __restrict__ Wq, const float* __restrict__ Wk,
    _Float16* __restrict__ WQT, _Float16* __restrict__ WKT) {
  __shared__ float tile[64][129];
  const int bid = blockIdx.x;
  const float* W = (bid >= 8) ? Wk : Wq;
  _Float16* WT = (bid >= 8) ? WKT : WQT;
  const int d0 = (bid & 7) * 64;
  const int t = threadIdx.x;
  #pragma unroll
  for (int j = 0; j < 32; ++j) {
    const int idx = t + j * 256;
    const int r = idx >> 7, c = idx & 127;
    tile[r][c] = W[(size_t)(d0 + r) * NH + c];
  }
  __syncthreads();
  #pragma unroll
  for (int j = 0; j < 32; ++j) {
    const int idx = t + j * 256;
    const int h = idx >> 6, r = idx & 63;
    WT[(size_t)h * ND + d0 + r] = (_Float16)tile[r][h];
  }
}

// ---------------------------------------------------------------------------
// Kernel 1: projection via MFMA fp16 + exp2 epilogue.
// Rows 0..1023 = queries->EQ, 1024..5119 = keys->EK. Block = 16 rows, 4
// waves; wave w owns n-tiles {2w, 2w+1} (h = w*32..w*32+31). K-dim = 512.
// A-frag: lane l holds X[row0 + (l&15)][d + (l>>4)*8 ..+8] (cvt fp32->fp16).
// B-frag: lane l holds WT[h0 + (l&15)][d + (l>>4)*8 ..+8].
// D: col = l&15, row = (l>>4)*4 + r (verified layout, passing since R3).
// ---------------------------------------------------------------------------
__global__ __launch_bounds__(256) void proj_mfma_kernel(
    const float* __restrict__ queries, const float* __restrict__ keys,
    const _Float16* __restrict__ WQT, const _Float16* __restrict__ WKT,
    float* __restrict__ EQ, float* __restrict__ EK) {
  const int bid = blockIdx.x;
  const int row0 = bid * 16;
  const bool is_q = row0 < NB * NQ;
  const float* X = is_q ? queries : (keys - (size_t)NB * NQ * ND);
  const _Float16* WT = is_q ? WQT : WKT;
  float* Y = is_q ? (EQ - (size_t)0) : (EK - (size_t)NB * NQ * NH);

  const int w = threadIdx.x >> 6;
  const int l = threadIdx.x & 63;
  const int h0 = w * 32;

  const float* xrow = X + (size_t)(row0 + (l & 15)) * ND + (l >> 4) * 8;
  const _Float16* wt0 = WT + (size_t)(h0 + (l & 15)) * ND + (l >> 4) * 8;
  const _Float16* wt1 = wt0 + 16 * ND;

  f32x4_t acc0 = {0.f, 0.f, 0.f, 0.f};
  f32x4_t acc1 = {0.f, 0.f, 0.f, 0.f};
  #pragma unroll 4
  for (int d = 0; d < ND; d += 32) {
    const float4 x0 = *(const float4*)(xrow + d);
    const float4 x1 = *(const float4*)(xrow + d + 4);
    half8_t a;
    a[0] = (_Float16)x0.x; a[1] = (_Float16)x0.y;
    a[2] = (_Float16)x0.z; a[3] = (_Float16)x0.w;
    a[4] = (_Float16)x1.x; a[5] = (_Float16)x1.y;
    a[6] = (_Float16)x1.z; a[7] = (_Float16)x1.w;
    const half8_t b0 = *(const half8_t*)(wt0 + d);
    const half8_t b1 = *(const half8_t*)(wt1 + d);
    acc0 = __builtin_amdgcn_mfma_f32_16x16x32_f16(a, b0, acc0, 0, 0, 0);
    acc1 = __builtin_amdgcn_mfma_f32_16x16x32_f16(a, b1, acc1, 0, 0, 0);
  }
  const int mrow = row0 + (l >> 4) * 4;
  const int hcol = h0 + (l & 15);
  #pragma unroll
  for (int r = 0; r < 4; ++r) {
    Y[(size_t)(mrow + r) * NH + hcol] = __builtin_exp2f(TANH_C * acc0[r]);
    Y[(size_t)(mrow + r) * NH + hcol + 16] = __builtin_exp2f(TANH_C * acc1[r]);
  }
}

// ---------------------------------------------------------------------------
// Kernel 2: scores = Wsum - 2*sum_h wv[h]/(EQ[q,h]*EK[k,h]+1).  No exp.
// Block = (b, 4 q-rows, 256-k chunk). EK staged in LDS coalesced with XOR
// swizzle (float4 idx = row*32 + (slot ^ (row&7))) -> conflict-free reads.
// ---------------------------------------------------------------------------
__global__ __launch_bounds__(256) void scores_kernel(
    const float* __restrict__ EQ, const float* __restrict__ EK,
    const float* __restrict__ wv, const int* __restrict__ vlen,
    float* __restrict__ scores) {
  constexpr int TQ = 4, KC = 256, KT = 64;
  __shared__ float eqs[TQ][NH];
  __shared__ float wvs[NH];
  __shared__ float khs[KT * NH];  // 32 KB, XOR-swizzled float4 layout

  const int bid = blockIdx.x;
  const int kc = bid & 3;
  const int qt = (bid >> 2) & 63;
  const int b = bid >> 8;
  const int q0 = qt * TQ;
  const int t = threadIdx.x;
  const int vl = vlen[b];

  if (kc * KC >= vl) {  // fully masked chunk: zeros, no work
    const int r = t >> 6, c = (t & 63) * 4;
    *(float4*)(scores + (size_t)(b * NQ + q0 + r) * NK + kc * KC + c) =
        make_float4(0.f, 0.f, 0.f, 0.f);
    return;
  }

  if (t < TQ * NH / 4) {
    const int r = t >> 5, c = t & 31;
    ((float4*)&eqs[r][0])[c] =
        ((const float4*)(EQ + (size_t)(b * NQ + q0 + r) * NH))[c];
  }
  if (t >= 224) ((float4*)wvs)[t - 224] = ((const float4*)wv)[t - 224];
  __syncthreads();

  const int myq = t >> 6;
  const int l = t & 63;

  float Wsum = wvs[l] + wvs[l + 64];
  #pragma unroll
  for (int off = 32; off; off >>= 1) Wsum += __shfl_xor(Wsum, off);

  float4* khs4 = (float4*)khs;
  const float4* eq4 = (const float4*)&eqs[myq][0];
  const float4* wv4 = (const float4*)wvs;

  for (int c0 = 0; c0 < KC; c0 += KT) {
    __syncthreads();
    {
      const float4* src =
          (const float4*)(EK + ((size_t)b * NK + kc * KC + c0) * NH);
      #pragma unroll
      for (int i = 0; i < 8; ++i) {
        const int idx = t + i * 256;
        const int row = idx >> 5, slot = idx & 31;
        khs4[row * 32 + (slot ^ (row & 7))] = src[idx];
      }
    }
    __syncthreads();
    float acc = 0.f;
    const int lbase = l * 32;
    const int lx = l & 7;
    #pragma unroll
    for (int slot = 0; slot < 32; ++slot) {
      const float4 e = khs4[lbase + (slot ^ lx)];
      const float4 q4 = eq4[slot];
      const float4 w4 = wv4[slot];
      acc = fmaf(w4.x, __builtin_amdgcn_rcpf(fmaf(q4.x, e.x, 1.f)), acc);
      acc = fmaf(w4.y, __builtin_amdgcn_rcpf(fmaf(q4.y, e.y, 1.f)), acc);
      acc = fmaf(w4.z, __builtin_amdgcn_rcpf(fmaf(q4.z, e.z, 1.f)), acc);
      acc = fmaf(w4.w, __builtin_amdgcn_rcpf(fmaf(q4.w, e.w, 1.f)), acc);
    }
    const int k = kc * KC + c0 + l;
    scores[(size_t)(b * NQ + q0 + myq) * NK + k] =
        (k < vl) ? (Wsum - 2.f * acc) : 0.f;
  }
}

// ---------------------------------------------------------------------------
// Kernel 3: softmax over each 1024 row of scores -> fp16 attn. One wave/row.
// ---------------------------------------------------------------------------
__global__ __launch_bounds__(64) void softmax_kernel(
    const float* __restrict__ scores, _Float16* __restrict__ attn_h) {
  const int row = blockIdx.x;
  const float4* a = (const float4*)(scores + (size_t)row * NK);
  const int lane = threadIdx.x;
  float4 v[4];
  #pragma unroll
  for (int j = 0; j < 4; ++j) v[j] = a[lane + 64 * j];
  float m = -1e30f;
  #pragma unroll
  for (int j = 0; j < 4; ++j)
    m = fmaxf(m, fmaxf(fmaxf(v[j].x, v[j].y), fmaxf(v[j].z, v[j].w)));
  #pragma unroll
  for (int off = 32; off; off >>= 1) m = fmaxf(m, __shfl_xor(m, off));
  const float c = 1.4426950408889634f;
  float sum = 0.f;
  #pragma unroll
  for (int j = 0; j < 4; ++j) {
    v[j].x = __builtin_exp2f(c * (v[j].x - m));
    v[j].y = __builtin_exp2f(c * (v[j].y - m));
    v[j].z = __builtin_exp2f(c * (v[j].z - m));
    v[j].w = __builtin_exp2f(c * (v[j].w - m));
    sum += v[j].x + v[j].y + v[j].z + v[j].w;
  }
  #pragma unroll
  for (int off = 32; off; off >>= 1) sum += __shfl_xor(sum, off);
  const float inv = 1.0f / sum;
  _Float16* orow = attn_h + (size_t)row * NK;
  #pragma unroll
  for (int j = 0; j < 4; ++j) {
    half4_t h;
    h[0] = (_Float16)(v[j].x * inv);
    h[1] = (_Float16)(v[j].y * inv);
    h[2] = (_Float16)(v[j].z * inv);
    h[3] = (_Float16)(v[j].w * inv);
    *(half4_t*)(orow + 256 * j + lane * 4) = h;
  }
}

// ---------------------------------------------------------------------------
// Kernel 4: transpose+convert values (B,K,D) fp32 -> vT (B,D,K) fp16.
// ---------------------------------------------------------------------------
__global__ __launch_bounds__(256) void vt_convert_kernel(
    const float* __restrict__ values, _Float16* __restrict__ vT) {
  __shared__ float tile[64][65];
  const int bid = blockIdx.x;
  const int dt = bid & 7;
  const int kt = (bid >> 3) & 15;
  const int b = bid >> 7;
  const int k0 = kt * 64, d0 = dt * 64;
  const int t = threadIdx.x;
  {
    const int kl = t >> 4, dl4 = (t & 15) * 4;
    #pragma unroll
    for (int i = 0; i < 4; ++i) {
      const float4 v = *(const float4*)(
          values + ((size_t)(b * NK + k0 + kl + i * 16)) * ND + d0 + dl4);
      tile[dl4 + 0][kl + i * 16] = v.x;
      tile[dl4 + 1][kl + i * 16] = v.y;
      tile[dl4 + 2][kl + i * 16] = v.z;
      tile[dl4 + 3][kl + i * 16] = v.w;
    }
  }
  __syncthreads();
  const int dr = t >> 2, kc = (t & 3) * 16;
  half8_t h0, h1;
  #pragma unroll
  for (int ii = 0; ii < 8; ++ii) {
    h0[ii] = (_Float16)tile[dr][kc + ii];
    h1[ii] = (_Float16)tile[dr][kc + 8 + ii];
  }
  _Float16* dst = vT + ((size_t)(b * ND + d0 + dr)) * NK + k0 + kc;
  *(half8_t*)dst = h0;
  *(half8_t*)(dst + 8) = h1;
}

// ---------------------------------------------------------------------------
// Kernel 5: zero d_out (replaces 40us rocclr fillBuffer). 512 blocks.
// ---------------------------------------------------------------------------
__global__ __launch_bounds__(256) void zero_kernel(float4* __restrict__ p) {
  p[(size_t)blockIdx.x * 256 + threadIdx.x] =
      make_float4(0.f, 0.f, 0.f, 0.f);
}

// ---------------------------------------------------------------------------
// Kernel 6: PV via MFMA fp16, k-split by 4 (grid 1024). atomicAdd partials.
// ---------------------------------------------------------------------------
__global__ __launch_bounds__(256) void pv_mfma_kernel(
    const _Float16* __restrict__ attn_h, const _Float16* __restrict__ vT,
    float* __restrict__ out) {
  const int bid = blockIdx.x;
  const int kc  = bid & 3;
  const int nt8 = (bid >> 2) & 7;
  const int mt  = (bid >> 5) & 7;
  const int b   = bid >> 8;
  const int w = threadIdx.x >> 6;
  const int l = threadIdx.x & 63;
  const int mtile = w & 1;
  const int ntile0 = (w >> 1) * 2;
  const int q_lo = mt * 32 + mtile * 16;
  const int d_lo = nt8 * 64 + ntile0 * 16;
  const int k0 = kc * 256;

  const _Float16* arow =
      attn_h + ((size_t)(b * NQ + q_lo + (l & 15))) * NK + k0 + (l >> 4) * 8;
  const _Float16* brow0 =
      vT + ((size_t)(b * ND + d_lo + (l & 15))) * NK + k0 + (l >> 4) * 8;
  const _Float16* brow1 = brow0 + 16 * NK;

  f32x4_t acc0 = {0.f, 0.f, 0.f, 0.f};
  f32x4_t acc1 = {0.f, 0.f, 0.f, 0.f};
  #pragma unroll
  for (int ks = 0; ks < 256; ks += 32) {
    const half8_t a  = *(const half8_t*)(arow + ks);
    const half8_t b0 = *(const half8_t*)(brow0 + ks);
    const half8_t b1 = *(const half8_t*)(brow1 + ks);
    acc0 = __builtin_amdgcn_mfma_f32_16x16x32_f16(a, b0, acc0, 0, 0, 0);
    acc1 = __builtin_amdgcn_mfma_f32_16x16x32_f16(a, b1, acc1, 0, 0, 0);
  }
  const int mrow = q_lo + (l >> 4) * 4;
  const int dcol = d_lo + (l & 15);
  #pragma unroll
  for (int r = 0; r < 4; ++r) {
    atomicAdd(&out[(size_t)(b * NQ + mrow + r) * ND + dcol], acc0[r]);
    atomicAdd(&out[(size_t)(b * NQ + mrow + r) * ND + dcol + 16], acc1[r]);
  }
}

// ---------------------------------------------------------------------------
extern "C" void kernel_launch(void* const* d_in, const int* in_sizes, int n_in,
                              void* d_out, int out_size, void* d_ws, size_t ws_size,
                              hipStream_t stream) {
  const float* queries = (const float*)d_in[0];
  const float* keys    = (const float*)d_in[1];
  const float* values  = (const float*)d_in[2];
  const float* Wq      = (const float*)d_in[3];
  const float* Wk      = (const float*)d_in[4];
  const float* wv      = (const float*)d_in[5];
  const int*   vlen    = (const int*)d_in[6];
  float* out = (float*)d_out;

  // ws overlays (peak 6.5 MB):
  //   EQ | EK | scores-region
  //   WQT/WKT live in scores-region only until proj completes (then dead).
  //   attn_h overlays EK after scores_kernel; vT overlays scores after softmax.
  float* EQ = (float*)d_ws;
  float* EK = EQ + (size_t)NB * NQ * NH;
  float* scores = EK + (size_t)NB * NK * NH;
  _Float16* attn_h = (_Float16*)EK;
  _Float16* vT = (_Float16*)scores;
  _Float16* WQT = (_Float16*)scores;           // 128x512 fp16
  _Float16* WKT = WQT + (size_t)NH * ND;       // 128x512 fp16

  wt_convert_kernel<<<16, 256, 0, stream>>>(Wq, Wk, WQT, WKT);
  proj_mfma_kernel<<<(NB * NQ + NB * NK) / 16, 256, 0, stream>>>(
      queries, keys, WQT, WKT, EQ, EK);
  scores_kernel<<<NB * 64 * 4, 256, 0, stream>>>(EQ, EK, wv, vlen, scores);
  softmax_kernel<<<NB * NQ, 64, 0, stream>>>(scores, attn_h);
  vt_convert_kernel<<<512, 256, 0, stream>>>(values, vT);
  zero_kernel<<<512, 256, 0, stream>>>((float4*)out);
  pv_mfma_kernel<<<NB * 8 * 8 * 4, 256, 0, stream>>>(attn_h, vT, out);
}